// Round 14
// baseline (572.140 us; speedup 1.0000x reference)
//
#include <hip/hip_runtime.h>
#include <hip/hip_bf16.h>

typedef __attribute__((ext_vector_type(8))) short short8;
typedef __attribute__((ext_vector_type(4))) float f32x4;

#define MFMA(a, b, c) __builtin_amdgcn_mfma_f32_16x16x32_bf16((a), (b), (c), 0, 0, 0)

namespace {
constexpr int IMG = 256;
constexpr int NWIN = 1024;
constexpr float SCALE = 0.17677669529663687f;  // 32^-0.5
constexpr float L2E   = 1.4426950408889634f;   // log2(e)
}

__device__ __forceinline__ unsigned pack2(float a, float b) {
    __hip_bfloat162 h = __float22bfloat162_rn(make_float2(a, b));
    union { __hip_bfloat162 h; unsigned u; } v; v.h = h;
    return v.u;
}

// ============== merged prep: weight transposes + bias tables (1 launch) ======
// blocks 0..53:  w_qkv fp32[192][576] -> wqT bf16[576][192] (q rows pre-scaled)
// blocks 54..71: w_out fp32[192][192] -> woT bf16[192][192]
// blocks 72..167: bias tables (f32, *log2e; masked variant) + bq2
__global__ __launch_bounds__(256)
void prep_all(const float* __restrict__ w_qkv, const float* __restrict__ w_out,
              const float* __restrict__ rel_pos, const float* __restrict__ b_qkv,
              unsigned short* __restrict__ wqT, unsigned short* __restrict__ woT,
              float* __restrict__ biasf, float* __restrict__ bq2) {
    const int bx = blockIdx.x;
    const int t  = threadIdx.x;
    if (bx < 72) {
        __shared__ float tile[32][65];
        const float* in; unsigned short* out; int N, scale_n; float scale; int tx, ty;
        if (bx < 54) { in = w_qkv; out = wqT; N = 576; scale_n = 192; scale = SCALE; tx = bx % 9; ty = bx / 9; }
        else { const int b2 = bx - 54; in = w_out; out = woT; N = 192; scale_n = 0; scale = 1.0f; tx = b2 % 3; ty = b2 / 3; }
        const int nb = tx * 64, kb = ty * 32;
        const int tn = t & 63, tk = t >> 6;
#pragma unroll
        for (int p = 0; p < 8; ++p)
            tile[p * 4 + tk][tn] = in[(size_t)(kb + p * 4 + tk) * N + nb + tn];
        __syncthreads();
        const int n = t >> 2, kc = (t & 3) * 8;
        const float s = (nb + n) < scale_n ? scale : 1.0f;
        uint4 u;
        u.x = pack2(tile[kc + 0][n] * s, tile[kc + 1][n] * s);
        u.y = pack2(tile[kc + 2][n] * s, tile[kc + 3][n] * s);
        u.z = pack2(tile[kc + 4][n] * s, tile[kc + 5][n] * s);
        u.w = pack2(tile[kc + 6][n] * s, tile[kc + 7][n] * s);
        *(uint4*)(out + (size_t)(nb + n) * 192 + kb + kc) = u;
    } else {
        const int o = (bx - 72) * 256 + t;   // 0..24575
        const int k = o & 63, q = (o >> 6) & 63, h = o >> 12;
        const int qy = q >> 3, qx = q & 7, ky = k >> 3, kx = k & 7;
        const float bv = rel_pos[h * 225 + (qy - ky + 7) * 15 + (qx - kx + 7)] * L2E;
        biasf[o] = bv;
        const bool masked = (q < 4) != (k < 4);
        biasf[24576 + o] = masked ? -30000.0f : bv;
        if (bx == 72) {
            for (int i = t; i < 576; i += 256)
                bq2[i] = b_qkv[i] * (i < 192 ? SCALE : 1.0f);
        }
    }
}

// ====== fused: GEMM1 (bias C-init) + attention + GEMM2 (K-sliced) + store ====
__global__ __launch_bounds__(256, 3)
void wmsa_fused(const float* __restrict__ x,
                const float* __restrict__ bq2,
                const float* __restrict__ biasf,          // [2][24576] f32, *log2e
                const unsigned short* __restrict__ wqT,   // bf16 [576][192], q pre-scaled
                const unsigned short* __restrict__ woT,   // bf16 [192][192]
                const float* __restrict__ b_out,
                float* __restrict__ out) {
    __shared__ unsigned short x_s[64][200];   // 25.6 KB
    __shared__ unsigned short qp_s[64][72];   //  9.2 KB  (q / P-h0 / o both heads)
    __shared__ unsigned short kp_s[64][72];   //  9.2 KB  (k / P-h1)
    __shared__ unsigned short vT_s[64][72];   //  9.2 KB  -> 53248 B, 3 blocks/CU

    const int tid = threadIdx.x;
    const int w   = tid >> 6;
    const int l   = tid & 63;
    const int l15 = l & 15, lg = l >> 4;
    const int wing = blockIdx.x;
    const int b   = wing >> 10;
    const int win = wing & (NWIN - 1);
    const int wy  = win >> 5, wx = win & 31;
    const float* bias_t = biasf + ((win == NWIN - 1) ? 24576 : 0);

    // cross-group weight-fragment prefetch buffer (one group's 18 frags)
    short8 wfr[3][6];
    auto LOADW = [&](int gg) {
#pragma unroll
        for (int ci = 0; ci < 3; ++ci) {
            const int t2 = w + 4 * ci;
            const int which = t2 >> 2, sub = t2 & 3;
            const int hh = sub >> 1, d0 = (sub & 1) * 16;
            const unsigned short* wp =
                wqT + (size_t)(which * 192 + (2 * gg + hh) * 32 + d0 + l15) * 192 + lg * 8;
#pragma unroll
            for (int ks = 0; ks < 6; ++ks) wfr[ci][ks] = *(const short8*)(wp + ks * 32);
        }
    };

    // ---- stage x window (roll folded); prefetch group-0 weights in parallel ----
    {
        const int t2 = tid >> 2;               // token 0..63
        const int c0 = tid & 3;
        const int pr = ((wy << 3) + (t2 >> 3) + 4) & (IMG - 1);
        const int pc = ((wx << 3) + (t2 & 7) + 4) & (IMG - 1);
        const float* xrow = x + ((size_t)((b * IMG + pr) * IMG + pc)) * 192;
#pragma unroll
        for (int i = 0; i < 12; ++i) {
            const int c = c0 + 4 * i;          // 0..47
            const float4 xv = *reinterpret_cast<const float4*>(xrow + c * 4);
            uint2 pk; pk.x = pack2(xv.x, xv.y); pk.y = pack2(xv.z, xv.w);
            *(uint2*)(&x_s[t2][c * 4]) = pk;
        }
    }
    LOADW(0);
    __syncthreads();

    const int h_loc = w >> 1;
    const int qt0   = 2 * (w & 1);

    // GEMM2 accumulators, C-init with output bias
    f32x4 g2[3][4];
#pragma unroll
    for (int mi = 0; mi < 3; ++mi) {
        const float4 bo = *reinterpret_cast<const float4*>(b_out + 16 * (w + 4 * mi) + 4 * lg);
        const f32x4 c0 = {bo.x, bo.y, bo.z, bo.w};
#pragma unroll
        for (int nt = 0; nt < 4; ++nt) g2[mi][nt] = c0;
    }

#pragma unroll 1
    for (int g = 0; g < 3; ++g) {             // heads 2g, 2g+1
        // ==== phase 1: GEMM1 from prefetched wfr; bias via C-init ====
        f32x4 aq[3][4];
#pragma unroll
        for (int ci = 0; ci < 3; ++ci) {
            const int t2 = w + 4 * ci;
            const int which = t2 >> 2, sub = t2 & 3;
            const int hh = sub >> 1, d0 = (sub & 1) * 16;
            f32x4 c0;
            if (which < 2) {                   // transposed D[col][tok]: bias per row
                const float4 b4 = *reinterpret_cast<const float4*>(
                    bq2 + which * 192 + (2 * g + hh) * 32 + d0 + 4 * lg);
                c0 = f32x4{b4.x, b4.y, b4.z, b4.w};
            } else {                           // normal D[tok][vcol]: bias per col
                const float bb = bq2[384 + (2 * g + hh) * 32 + d0 + l15];
                c0 = f32x4{bb, bb, bb, bb};
            }
#pragma unroll
            for (int nt = 0; nt < 4; ++nt) aq[ci][nt] = c0;
        }

        __builtin_amdgcn_s_setprio(1);
#pragma unroll
        for (int ks = 0; ks < 6; ++ks) {
            short8 xf[4];
#pragma unroll
            for (int nt = 0; nt < 4; ++nt)
                xf[nt] = *(const short8*)(&x_s[16 * nt + l15][ks * 32 + lg * 8]);
#pragma unroll
            for (int ci = 0; ci < 3; ++ci) {
                const short8 wf = wfr[ci][ks];
                if (ci < 2 ? ((w + 4 * ci) >> 2) < 2 : ((w + 8) >> 2) < 2) {
#pragma unroll
                    for (int nt = 0; nt < 4; ++nt) aq[ci][nt] = MFMA(wf, xf[nt], aq[ci][nt]);
                } else {                       // v: normal orientation
#pragma unroll
                    for (int nt = 0; nt < 4; ++nt) aq[ci][nt] = MFMA(xf[nt], wf, aq[ci][nt]);
                }
            }
        }
        __builtin_amdgcn_s_setprio(0);

        // epilogue (no adds/scales: bias pre-init, q pre-scaled)
#pragma unroll
        for (int ci = 0; ci < 3; ++ci) {
            const int t2 = w + 4 * ci;
            const int which = t2 >> 2, sub = t2 & 3;
            const int hh = sub >> 1, d0 = (sub & 1) * 16;
            if (which < 2) {                   // lane: col=tok, rows = 4 qkv-cols
                const int rbase = hh * 32 + d0 + 4 * lg;
#pragma unroll
                for (int nt = 0; nt < 4; ++nt) {
                    const int tok = 16 * nt + l15;
                    uint2 pk;
                    pk.x = pack2(aq[ci][nt][0], aq[ci][nt][1]);
                    pk.y = pack2(aq[ci][nt][2], aq[ci][nt][3]);
                    if (which == 0) *(uint2*)(&qp_s[tok][rbase]) = pk;
                    else            *(uint2*)(&kp_s[tok][rbase]) = pk;
                }
            } else {                           // v: lane holds 4 consecutive toks at one d
                const int dcol = hh * 32 + d0 + l15;
#pragma unroll
                for (int nt = 0; nt < 4; ++nt) {
                    uint2 pk;
                    pk.x = pack2(aq[ci][nt][0], aq[ci][nt][1]);
                    pk.y = pack2(aq[ci][nt][2], aq[ci][nt][3]);
                    *(uint2*)(&vT_s[dcol][16 * nt + 4 * lg]) = pk;
                }
            }
        }
        __syncthreads();   // A: q/k/vT ready

        // ==== phase 2a: S^T = MFMA(kf, qf): rows=k-tokens, cols=q-tokens ====
        short8 qf[2], kf[4];
#pragma unroll
        for (int mq = 0; mq < 2; ++mq)
            qf[mq] = *(const short8*)(&qp_s[16 * (qt0 + mq) + l15][h_loc * 32 + lg * 8]);
#pragma unroll
        for (int nt = 0; nt < 4; ++nt)
            kf[nt] = *(const short8*)(&kp_s[16 * nt + l15][h_loc * 32 + lg * 8]);
        f32x4 s[2][4];
        const f32x4 z = {0.f, 0.f, 0.f, 0.f};
        __builtin_amdgcn_s_setprio(1);
#pragma unroll
        for (int mq = 0; mq < 2; ++mq)
#pragma unroll
            for (int nt = 0; nt < 4; ++nt) s[mq][nt] = MFMA(kf[nt], qf[mq], z);
        __builtin_amdgcn_s_setprio(0);
        __syncthreads();   // B: q/k dead -> buffers recycle as P (then o)

        // prefetch next group's weights NOW: longest barrier-free window
        // (softmax+PV ~600-900 cyc) before the vmcnt drain at barrier D.
        if (g < 2) LOADW(g + 1);

        // ==== phase 2b: swapped softmax into own p_buf ====
        unsigned short (*p_buf)[72] = (h_loc == 0) ? qp_s : kp_s;
        const int h = 2 * g + h_loc;
        float ri[2];
#pragma unroll
        for (int mq = 0; mq < 2; ++mq) {
            const int q = 16 * (qt0 + mq) + l15;
            const float* bq = bias_t + ((h * 64 + q) << 6) + 4 * lg;
            float e[4][4], sum = 0.f;
#pragma unroll
            for (int nt = 0; nt < 4; ++nt) {
                const float4 bb = *(const float4*)(bq + 16 * nt);
                e[nt][0] = __builtin_exp2f(fmaf(s[mq][nt][0], L2E, bb.x));
                e[nt][1] = __builtin_exp2f(fmaf(s[mq][nt][1], L2E, bb.y));
                e[nt][2] = __builtin_exp2f(fmaf(s[mq][nt][2], L2E, bb.z));
                e[nt][3] = __builtin_exp2f(fmaf(s[mq][nt][3], L2E, bb.w));
                sum += (e[nt][0] + e[nt][1]) + (e[nt][2] + e[nt][3]);
            }
            sum += __shfl_xor(sum, 16);
            sum += __shfl_xor(sum, 32);
            ri[mq] = __builtin_amdgcn_rcpf(sum);
#pragma unroll
            for (int nt = 0; nt < 4; ++nt) {
                uint2 pk;
                pk.x = pack2(e[nt][0], e[nt][1]);
                pk.y = pack2(e[nt][2], e[nt][3]);
                *(uint2*)(&p_buf[q][16 * nt + 4 * lg]) = pk;
            }
        }

        // ==== phase 3: O^T = V^T P^T; o -> own p_buf rows (toks), cols 0..31 ====
        f32x4 o[2][2];
#pragma unroll
        for (int dm = 0; dm < 2; ++dm)
#pragma unroll
            for (int qn = 0; qn < 2; ++qn) o[dm][qn] = z;
        __builtin_amdgcn_s_setprio(1);
#pragma unroll
        for (int ks2 = 0; ks2 < 2; ++ks2) {
            short8 pf[2];
#pragma unroll
            for (int qn = 0; qn < 2; ++qn)
                pf[qn] = *(const short8*)(&p_buf[16 * (qt0 + qn) + l15][ks2 * 32 + lg * 8]);
#pragma unroll
            for (int dm = 0; dm < 2; ++dm) {
                const short8 vf = *(const short8*)(&vT_s[h_loc * 32 + 16 * dm + l15][ks2 * 32 + lg * 8]);
#pragma unroll
                for (int qn = 0; qn < 2; ++qn) o[dm][qn] = MFMA(vf, pf[qn], o[dm][qn]);
            }
        }
        __builtin_amdgcn_s_setprio(0);
        // own-wave in-order DS: pf reads of these rows complete before o overwrite
#pragma unroll
        for (int dm = 0; dm < 2; ++dm)
#pragma unroll
            for (int qn = 0; qn < 2; ++qn) {
                const int tok = 16 * (qt0 + qn) + l15;
                const float rr = ri[qn];
                uint2 pk;
                pk.x = pack2(o[dm][qn][0] * rr, o[dm][qn][1] * rr);
                pk.y = pack2(o[dm][qn][2] * rr, o[dm][qn][3] * rr);
                *(uint2*)(&p_buf[tok][16 * dm + 4 * lg]) = pk;
            }
        __syncthreads();   // D: o (both heads) staged across qp_s/kp_s

        // ==== phase 4: GEMM2 K-slice for this group's 64 channels ====
        __builtin_amdgcn_s_setprio(1);
#pragma unroll
        for (int ks2 = 0; ks2 < 2; ++ks2) {
            short8 bfr[4];
#pragma unroll
            for (int nt = 0; nt < 4; ++nt)
                bfr[nt] = (ks2 == 0)
                    ? *(const short8*)(&qp_s[16 * nt + l15][lg * 8])
                    : *(const short8*)(&kp_s[16 * nt + l15][lg * 8]);
#pragma unroll
            for (int mi = 0; mi < 3; ++mi) {
                const int oct = w + 4 * mi;
                const short8 af = *(const short8*)(
                    woT + (size_t)(16 * oct + l15) * 192 + g * 64 + ks2 * 32 + lg * 8);
#pragma unroll
                for (int nt = 0; nt < 4; ++nt) g2[mi][nt] = MFMA(af, bfr[nt], g2[mi][nt]);
            }
        }
        __builtin_amdgcn_s_setprio(0);
        if (g < 2) __syncthreads();   // E: phase-4 reads done before next phase-1 writes
    }

    // ==== final store: D[oc][tok]; 12 float4 stores (bias already in C-init) ====
#pragma unroll
    for (int nt = 0; nt < 4; ++nt) {
        const int tok = 16 * nt + l15;
        const int pr = ((wy << 3) + (tok >> 3) + 4) & (IMG - 1);
        const int pc = ((wx << 3) + (tok & 7) + 4) & (IMG - 1);
        float* orow = out + (size_t)((b * IMG + pr) * IMG + pc) * 192;
#pragma unroll
        for (int mi = 0; mi < 3; ++mi) {
            const int oc0 = 16 * (w + 4 * mi) + 4 * lg;
            *reinterpret_cast<float4*>(orow + oc0) =
                make_float4(g2[mi][nt][0], g2[mi][nt][1], g2[mi][nt][2], g2[mi][nt][3]);
        }
    }
}

extern "C" void kernel_launch(void* const* d_in, const int* in_sizes, int n_in,
                              void* d_out, int out_size, void* d_ws, size_t ws_size,
                              hipStream_t stream) {
    (void)in_sizes; (void)n_in; (void)out_size; (void)ws_size;
    const float* x       = (const float*)d_in[0];
    const float* w_qkv   = (const float*)d_in[1];
    const float* b_qkv   = (const float*)d_in[2];
    const float* rel_pos = (const float*)d_in[3];
    const float* w_out   = (const float*)d_in[4];
    const float* b_out   = (const float*)d_in[5];
    float* out = (float*)d_out;

    unsigned short* wqT   = (unsigned short*)d_ws;       // 110592 hw
    unsigned short* woT   = wqT + 576 * 192;             //  36864 hw
    float*          biasf = (float*)(woT + 192 * 192);   //  2*24576 f32
    float*          bq2   = biasf + 2 * 24576;           //  576 f32

    prep_all<<<dim3(168), dim3(256), 0, stream>>>(
        w_qkv, w_out, rel_pos, b_qkv, wqT, woT, biasf, bq2);

    wmsa_fused<<<dim3(4 * NWIN), dim3(256), 0, stream>>>(
        x, bq2, biasf, wqT, woT, b_out, out);
}

// Round 15
// 277.297 us; speedup vs baseline: 2.0633x; 2.0633x over previous
//
#include <hip/hip_runtime.h>
#include <hip/hip_bf16.h>

typedef __attribute__((ext_vector_type(8))) short short8;
typedef __attribute__((ext_vector_type(4))) float f32x4;

#define MFMA(a, b, c) __builtin_amdgcn_mfma_f32_16x16x32_bf16((a), (b), (c), 0, 0, 0)

namespace {
constexpr int IMG = 256;
constexpr int NWIN = 1024;
constexpr float SCALE = 0.17677669529663687f;  // 32^-0.5
constexpr float L2E   = 1.4426950408889634f;   // log2(e)
}

__device__ __forceinline__ unsigned pack2(float a, float b) {
    __hip_bfloat162 h = __float22bfloat162_rn(make_float2(a, b));
    union { __hip_bfloat162 h; unsigned u; } v; v.h = h;
    return v.u;
}

// ============== merged prep: weight transposes + bias tables (1 launch) ======
__global__ __launch_bounds__(256)
void prep_all(const float* __restrict__ w_qkv, const float* __restrict__ w_out,
              const float* __restrict__ rel_pos, const float* __restrict__ b_qkv,
              unsigned short* __restrict__ wqT, unsigned short* __restrict__ woT,
              float* __restrict__ biasf, float* __restrict__ bq2) {
    const int bx = blockIdx.x;
    const int t  = threadIdx.x;
    if (bx < 72) {
        __shared__ float tile[32][65];
        const float* in; unsigned short* out; int N, scale_n; float scale; int tx, ty;
        if (bx < 54) { in = w_qkv; out = wqT; N = 576; scale_n = 192; scale = SCALE; tx = bx % 9; ty = bx / 9; }
        else { const int b2 = bx - 54; in = w_out; out = woT; N = 192; scale_n = 0; scale = 1.0f; tx = b2 % 3; ty = b2 / 3; }
        const int nb = tx * 64, kb = ty * 32;
        const int tn = t & 63, tk = t >> 6;
#pragma unroll
        for (int p = 0; p < 8; ++p)
            tile[p * 4 + tk][tn] = in[(size_t)(kb + p * 4 + tk) * N + nb + tn];
        __syncthreads();
        const int n = t >> 2, kc = (t & 3) * 8;
        const float s = (nb + n) < scale_n ? scale : 1.0f;
        uint4 u;
        u.x = pack2(tile[kc + 0][n] * s, tile[kc + 1][n] * s);
        u.y = pack2(tile[kc + 2][n] * s, tile[kc + 3][n] * s);
        u.z = pack2(tile[kc + 4][n] * s, tile[kc + 5][n] * s);
        u.w = pack2(tile[kc + 6][n] * s, tile[kc + 7][n] * s);
        *(uint4*)(out + (size_t)(nb + n) * 192 + kb + kc) = u;
    } else {
        const int o = (bx - 72) * 256 + t;   // 0..24575
        const int k = o & 63, q = (o >> 6) & 63, h = o >> 12;
        const int qy = q >> 3, qx = q & 7, ky = k >> 3, kx = k & 7;
        const float bv = rel_pos[h * 225 + (qy - ky + 7) * 15 + (qx - kx + 7)] * L2E;
        biasf[o] = bv;
        const bool masked = (q < 4) != (k < 4);
        biasf[24576 + o] = masked ? -30000.0f : bv;
        if (bx == 72) {
            for (int i = t; i < 576; i += 256)
                bq2[i] = b_qkv[i] * (i < 192 ? SCALE : 1.0f);
        }
    }
}

// ====== fused: GEMM1 (bias C-init) + attention + GEMM2 (K-sliced) + store ====
// (R13 kernel, verbatim: the 271 us best-known state. R14's cross-group wfr
// prefetch spilled to scratch (WRITE 1.27 GB) and is reverted.)
__global__ __launch_bounds__(256, 3)
void wmsa_fused(const float* __restrict__ x,
                const float* __restrict__ bq2,
                const float* __restrict__ biasf,          // [2][24576] f32, *log2e
                const unsigned short* __restrict__ wqT,   // bf16 [576][192], q pre-scaled
                const unsigned short* __restrict__ woT,   // bf16 [192][192]
                const float* __restrict__ b_out,
                float* __restrict__ out) {
    __shared__ unsigned short x_s[64][200];   // 25.6 KB
    __shared__ unsigned short qp_s[64][72];   //  9.2 KB  (q / P-h0 / o-h2g)
    __shared__ unsigned short kp_s[64][72];   //  9.2 KB  (k / P-h1 / o-h2g+1)
    __shared__ unsigned short vT_s[64][72];   //  9.2 KB  -> 53248 B, 3 blocks/CU

    const int tid = threadIdx.x;
    const int w   = tid >> 6;
    const int l   = tid & 63;
    const int l15 = l & 15, lg = l >> 4;
    const int wing = blockIdx.x;
    const int b   = wing >> 10;
    const int win = wing & (NWIN - 1);
    const int wy  = win >> 5, wx = win & 31;
    const float* bias_t = biasf + ((win == NWIN - 1) ? 24576 : 0);

    // ---- stage x window: thread = (row, chunk); no div/mod, coalesced ----
    {
        const int t  = tid >> 2;               // token 0..63
        const int c0 = tid & 3;
        const int pr = ((wy << 3) + (t >> 3) + 4) & (IMG - 1);
        const int pc = ((wx << 3) + (t & 7) + 4) & (IMG - 1);
        const float* xrow = x + ((size_t)((b * IMG + pr) * IMG + pc)) * 192;
#pragma unroll
        for (int i = 0; i < 12; ++i) {
            const int c = c0 + 4 * i;          // 0..47
            const float4 xv = *reinterpret_cast<const float4*>(xrow + c * 4);
            uint2 pk; pk.x = pack2(xv.x, xv.y); pk.y = pack2(xv.z, xv.w);
            *(uint2*)(&x_s[t][c * 4]) = pk;
        }
    }
    __syncthreads();

    const int h_loc = w >> 1;
    const int qt0   = 2 * (w & 1);

    // GEMM2 accumulators, C-init with output bias (rows = oc = 16*(w+4mi)+4lg+j)
    f32x4 g2[3][4];
#pragma unroll
    for (int mi = 0; mi < 3; ++mi) {
        const float4 bo = *reinterpret_cast<const float4*>(b_out + 16 * (w + 4 * mi) + 4 * lg);
        const f32x4 c0 = {bo.x, bo.y, bo.z, bo.w};
#pragma unroll
        for (int nt = 0; nt < 4; ++nt) g2[mi][nt] = c0;
    }

#pragma unroll 1
    for (int g = 0; g < 3; ++g) {             // heads 2g, 2g+1
        // ==== phase 1: GEMM1; wave owns col-tiles {w, w+4, w+8}; bias via C-init
        f32x4 aq[3][4];
        const unsigned short* wp[3];
#pragma unroll
        for (int ci = 0; ci < 3; ++ci) {
            const int t = w + 4 * ci;
            const int which = t >> 2, sub = t & 3;
            const int hh = sub >> 1, d0 = (sub & 1) * 16;
            const int grow = which * 192 + (2 * g + hh) * 32 + d0 + l15;
            wp[ci] = wqT + (size_t)grow * 192 + lg * 8;
            f32x4 c0;
            if (which < 2) {                   // transposed D[col][tok]: bias per row
                const float4 b4 = *reinterpret_cast<const float4*>(
                    bq2 + which * 192 + (2 * g + hh) * 32 + d0 + 4 * lg);
                c0 = f32x4{b4.x, b4.y, b4.z, b4.w};
            } else {                           // normal D[tok][vcol]: bias per col
                const float bb = bq2[384 + (2 * g + hh) * 32 + d0 + l15];
                c0 = f32x4{bb, bb, bb, bb};
            }
#pragma unroll
            for (int nt = 0; nt < 4; ++nt) aq[ci][nt] = c0;
        }

        __builtin_amdgcn_s_setprio(1);
#pragma unroll
        for (int ks = 0; ks < 6; ++ks) {
            short8 xf[4];
#pragma unroll
            for (int nt = 0; nt < 4; ++nt)
                xf[nt] = *(const short8*)(&x_s[16 * nt + l15][ks * 32 + lg * 8]);
#pragma unroll
            for (int ci = 0; ci < 3; ++ci) {
                const short8 wf = *(const short8*)wp[ci];
                wp[ci] += 32;
                if (ci < 2 ? ((w + 4 * ci) >> 2) < 2 : ((w + 8) >> 2) < 2) {
#pragma unroll
                    for (int nt = 0; nt < 4; ++nt) aq[ci][nt] = MFMA(wf, xf[nt], aq[ci][nt]);
                } else {                       // v: normal orientation
#pragma unroll
                    for (int nt = 0; nt < 4; ++nt) aq[ci][nt] = MFMA(xf[nt], wf, aq[ci][nt]);
                }
            }
        }
        __builtin_amdgcn_s_setprio(0);

        // epilogue (no adds/scales: bias pre-init, q pre-scaled)
#pragma unroll
        for (int ci = 0; ci < 3; ++ci) {
            const int t = w + 4 * ci;
            const int which = t >> 2, sub = t & 3;
            const int hh = sub >> 1, d0 = (sub & 1) * 16;
            if (which < 2) {                   // lane: col=tok, rows = 4 qkv-cols
                const int rbase = hh * 32 + d0 + 4 * lg;
#pragma unroll
                for (int nt = 0; nt < 4; ++nt) {
                    const int tok = 16 * nt + l15;
                    uint2 pk;
                    pk.x = pack2(aq[ci][nt][0], aq[ci][nt][1]);
                    pk.y = pack2(aq[ci][nt][2], aq[ci][nt][3]);
                    if (which == 0) *(uint2*)(&qp_s[tok][rbase]) = pk;
                    else            *(uint2*)(&kp_s[tok][rbase]) = pk;
                }
            } else {                           // v: lane holds 4 consecutive toks at one d
                const int dcol = hh * 32 + d0 + l15;
#pragma unroll
                for (int nt = 0; nt < 4; ++nt) {
                    uint2 pk;
                    pk.x = pack2(aq[ci][nt][0], aq[ci][nt][1]);
                    pk.y = pack2(aq[ci][nt][2], aq[ci][nt][3]);
                    *(uint2*)(&vT_s[dcol][16 * nt + 4 * lg]) = pk;
                }
            }
        }
        __syncthreads();   // A: q/k/vT ready

        // ==== phase 2a: S^T = MFMA(kf, qf): rows=k-tokens, cols=q-tokens ====
        short8 qf[2], kf[4];
#pragma unroll
        for (int mq = 0; mq < 2; ++mq)
            qf[mq] = *(const short8*)(&qp_s[16 * (qt0 + mq) + l15][h_loc * 32 + lg * 8]);
#pragma unroll
        for (int nt = 0; nt < 4; ++nt)
            kf[nt] = *(const short8*)(&kp_s[16 * nt + l15][h_loc * 32 + lg * 8]);
        f32x4 s[2][4];
        const f32x4 z = {0.f, 0.f, 0.f, 0.f};
        __builtin_amdgcn_s_setprio(1);
#pragma unroll
        for (int mq = 0; mq < 2; ++mq)
#pragma unroll
            for (int nt = 0; nt < 4; ++nt) s[mq][nt] = MFMA(kf[nt], qf[mq], z);
        __builtin_amdgcn_s_setprio(0);
        __syncthreads();   // B: q/k dead -> buffers recycle as P (then o)

        // ==== phase 2b: swapped softmax into own p_buf ====
        unsigned short (*p_buf)[72] = (h_loc == 0) ? qp_s : kp_s;
        const int h = 2 * g + h_loc;
        float ri[2];
#pragma unroll
        for (int mq = 0; mq < 2; ++mq) {
            const int q = 16 * (qt0 + mq) + l15;
            const float* bq = bias_t + ((h * 64 + q) << 6) + 4 * lg;
            float e[4][4], sum = 0.f;
#pragma unroll
            for (int nt = 0; nt < 4; ++nt) {
                const float4 bb = *(const float4*)(bq + 16 * nt);
                e[nt][0] = __builtin_exp2f(fmaf(s[mq][nt][0], L2E, bb.x));
                e[nt][1] = __builtin_exp2f(fmaf(s[mq][nt][1], L2E, bb.y));
                e[nt][2] = __builtin_exp2f(fmaf(s[mq][nt][2], L2E, bb.z));
                e[nt][3] = __builtin_exp2f(fmaf(s[mq][nt][3], L2E, bb.w));
                sum += (e[nt][0] + e[nt][1]) + (e[nt][2] + e[nt][3]);
            }
            sum += __shfl_xor(sum, 16);
            sum += __shfl_xor(sum, 32);
            ri[mq] = __builtin_amdgcn_rcpf(sum);
#pragma unroll
            for (int nt = 0; nt < 4; ++nt) {
                uint2 pk;
                pk.x = pack2(e[nt][0], e[nt][1]);
                pk.y = pack2(e[nt][2], e[nt][3]);
                *(uint2*)(&p_buf[q][16 * nt + 4 * lg]) = pk;
            }
        }

        // ==== phase 3: O^T = V^T P^T; o -> own p_buf rows (toks), cols 0..31 ====
        f32x4 o[2][2];
#pragma unroll
        for (int dm = 0; dm < 2; ++dm)
#pragma unroll
            for (int qn = 0; qn < 2; ++qn) o[dm][qn] = z;
        __builtin_amdgcn_s_setprio(1);
#pragma unroll
        for (int ks2 = 0; ks2 < 2; ++ks2) {
            short8 pf[2];
#pragma unroll
            for (int qn = 0; qn < 2; ++qn)
                pf[qn] = *(const short8*)(&p_buf[16 * (qt0 + qn) + l15][ks2 * 32 + lg * 8]);
#pragma unroll
            for (int dm = 0; dm < 2; ++dm) {
                const short8 vf = *(const short8*)(&vT_s[h_loc * 32 + 16 * dm + l15][ks2 * 32 + lg * 8]);
#pragma unroll
                for (int qn = 0; qn < 2; ++qn) o[dm][qn] = MFMA(vf, pf[qn], o[dm][qn]);
            }
        }
        __builtin_amdgcn_s_setprio(0);
        // own-wave in-order DS: pf reads of these rows complete before o overwrite
#pragma unroll
        for (int dm = 0; dm < 2; ++dm)
#pragma unroll
            for (int qn = 0; qn < 2; ++qn) {
                const int tok = 16 * (qt0 + qn) + l15;
                const float rr = ri[qn];
                uint2 pk;
                pk.x = pack2(o[dm][qn][0] * rr, o[dm][qn][1] * rr);
                pk.y = pack2(o[dm][qn][2] * rr, o[dm][qn][3] * rr);
                *(uint2*)(&p_buf[tok][16 * dm + 4 * lg]) = pk;
            }
        __syncthreads();   // D: o (both heads) staged across qp_s/kp_s

        // ==== phase 4: GEMM2 K-slice for this group's 64 channels ====
        __builtin_amdgcn_s_setprio(1);
#pragma unroll
        for (int ks2 = 0; ks2 < 2; ++ks2) {
            short8 bfr[4];
#pragma unroll
            for (int nt = 0; nt < 4; ++nt)
                bfr[nt] = (ks2 == 0)
                    ? *(const short8*)(&qp_s[16 * nt + l15][lg * 8])
                    : *(const short8*)(&kp_s[16 * nt + l15][lg * 8]);
#pragma unroll
            for (int mi = 0; mi < 3; ++mi) {
                const int oct = w + 4 * mi;
                const short8 af = *(const short8*)(
                    woT + (size_t)(16 * oct + l15) * 192 + g * 64 + ks2 * 32 + lg * 8);
#pragma unroll
                for (int nt = 0; nt < 4; ++nt) g2[mi][nt] = MFMA(af, bfr[nt], g2[mi][nt]);
            }
        }
        __builtin_amdgcn_s_setprio(0);
        if (g < 2) __syncthreads();   // E: phase-4 reads done before next phase-1 writes
    }

    // ==== final store: D[oc][tok]; 12 float4 stores (bias already in C-init) ====
#pragma unroll
    for (int nt = 0; nt < 4; ++nt) {
        const int tok = 16 * nt + l15;
        const int pr = ((wy << 3) + (tok >> 3) + 4) & (IMG - 1);
        const int pc = ((wx << 3) + (tok & 7) + 4) & (IMG - 1);
        float* orow = out + (size_t)((b * IMG + pr) * IMG + pc) * 192;
#pragma unroll
        for (int mi = 0; mi < 3; ++mi) {
            const int oc0 = 16 * (w + 4 * mi) + 4 * lg;
            *reinterpret_cast<float4*>(orow + oc0) =
                make_float4(g2[mi][nt][0], g2[mi][nt][1], g2[mi][nt][2], g2[mi][nt][3]);
        }
    }
}

extern "C" void kernel_launch(void* const* d_in, const int* in_sizes, int n_in,
                              void* d_out, int out_size, void* d_ws, size_t ws_size,
                              hipStream_t stream) {
    (void)in_sizes; (void)n_in; (void)out_size; (void)ws_size;
    const float* x       = (const float*)d_in[0];
    const float* w_qkv   = (const float*)d_in[1];
    const float* b_qkv   = (const float*)d_in[2];
    const float* rel_pos = (const float*)d_in[3];
    const float* w_out   = (const float*)d_in[4];
    const float* b_out   = (const float*)d_in[5];
    float* out = (float*)d_out;

    unsigned short* wqT   = (unsigned short*)d_ws;       // 110592 hw
    unsigned short* woT   = wqT + 576 * 192;             //  36864 hw
    float*          biasf = (float*)(woT + 192 * 192);   //  2*24576 f32
    float*          bq2   = biasf + 2 * 24576;           //  576 f32

    prep_all<<<dim3(168), dim3(256), 0, stream>>>(
        w_qkv, w_out, rel_pos, b_qkv, wqT, woT, biasf, bq2);

    wmsa_fused<<<dim3(4 * NWIN), dim3(256), 0, stream>>>(
        x, bq2, biasf, wqT, woT, b_out, out);
}